// Round 3
// baseline (399.194 us; speedup 1.0000x reference)
//
#include <hip/hip_runtime.h>
#include <math.h>

#define NN 25000
#define EE 300000
#define NT 1563          // ceil(25000/16)   (tail tiles)
#define NT64 391         // ceil(25000/64)   (ngemm tiles)
#define ET64 4688        // ceil(300000/64)  (egemm tiles)

typedef __attribute__((ext_vector_type(8))) short bf16x8;
typedef __attribute__((ext_vector_type(4))) float f32x4;
typedef __attribute__((ext_vector_type(2))) float f32x2;
typedef __attribute__((ext_vector_type(2))) __fp16 h2;

__device__ __forceinline__ unsigned short f2bf(float f) {
    union { float f; unsigned u; } a; a.f = f;
    unsigned r = (a.u + 0x7fffu + ((a.u >> 16) & 1u)) >> 16;   // RNE
    return (unsigned short)r;
}
__device__ __forceinline__ unsigned pack2(float lo, float hi) {
    return (unsigned)f2bf(lo) | ((unsigned)f2bf(hi) << 16);
}
__device__ __forceinline__ float bflo(unsigned p) {
    union { unsigned u; float f; } a; a.u = p << 16; return a.f;
}
__device__ __forceinline__ float bfhi(unsigned p) {
    union { unsigned u; float f; } a; a.u = p & 0xffff0000u; return a.f;
}
// pack 4 floats -> 4 fp8(e4m3 OCP) in one uint
__device__ __forceinline__ unsigned packfp8x4(float a, float b, float c, float d) {
    int v = __builtin_amdgcn_cvt_pk_fp8_f32(a, b, 0, 0);
    v = __builtin_amdgcn_cvt_pk_fp8_f32(c, d, v, 1);
    return (unsigned)v;
}
// pack 2 floats -> packed f16 pair (uint)
__device__ __forceinline__ unsigned pkh(float lo, float hi) {
    h2 r = __builtin_amdgcn_cvt_pkrtz(lo, hi);
    return __builtin_bit_cast(unsigned, r);
}
// 2 fp8 (word sel = template const) -> half2
template<bool HI>
__device__ __forceinline__ h2 fp8toh(unsigned v) {
#if __has_builtin(__builtin_amdgcn_cvt_scalef32_pk_f16_fp8)
    return __builtin_amdgcn_cvt_scalef32_pk_f16_fp8((int)v, 1.0f, HI);
#else
    f32x2 f = __builtin_amdgcn_cvt_pk_f32_fp8((int)v, HI);
    return __builtin_amdgcn_cvt_pkrtz(f.x, f.y);
#endif
}
// half2 dot with f32 accumulate
__device__ __forceinline__ float hdot(h2 a, h2 b, float c) {
#if __has_builtin(__builtin_amdgcn_fdot2)
    return __builtin_amdgcn_fdot2(a, b, c, false);
#else
    return c + (float)a[0] * (float)b[0] + (float)a[1] * (float)b[1];
#endif
}
__device__ __forceinline__ h2 hmax0(h2 a) {
    h2 z; z[0] = (__fp16)0.f; z[1] = (__fp16)0.f;
#if __has_builtin(__builtin_elementwise_max)
    return __builtin_elementwise_max(a, z);
#else
    h2 r;
    r[0] = a[0] > z[0] ? a[0] : z[0];
    r[1] = a[1] > z[1] ? a[1] : z[1];
    return r;
#endif
}

// ---------------------------------------------------------------------------
// head: fused egemm + ngemm (one dispatch; block role from blockIdx.x).
//  egemm (blocks [0,ET64)): gw8[g][1+e] = fp8( ew[e] @ W1g[64:128,:] ); row 0 = 0
//  ngemm: per source X in {eu,ei,et}:
//    preB = f16(X@Wa + ba), f16(X@Wb + bb)
//    JG[y][1+n] = [ fp8(X@W2) 64B | bf16(X) 128B ] (192 B rows); row 0 = 0
// ---------------------------------------------------------------------------
__global__ __launch_bounds__(256) void head_kernel(
    const float* __restrict__ ew,
    const float* __restrict__ eu, const float* __restrict__ ei, const float* __restrict__ et,
    const float* __restrict__ W1u, const float* __restrict__ W1i, const float* __restrict__ W1t,
    const float* __restrict__ W2u, const float* __restrict__ W2i, const float* __restrict__ W2t,
    const float* __restrict__ bu, const float* __restrict__ bi, const float* __restrict__ bt,
    unsigned char* __restrict__ gw8, unsigned* __restrict__ preB,
    unsigned char* __restrict__ JG)
{
    __shared__ __align__(16) unsigned short stA[64 * 72];
    __shared__ __align__(16) float cS[64 * 68];
    const int t = threadIdx.x;
    const int lane = t & 63, wv = t >> 6;
    const int l15 = lane & 15, quad = lane >> 4;
    const int cw = wv * 16 + l15;                 // this wave's output col
    const int bx = blockIdx.x;

    if (bx < ET64) {
        // ================= egemm role =================
        if (bx == 0 && t < 48) {   // zero row 0 of the 3 gw8 tables (64 B each)
            int w = t >> 4;
            ((unsigned*)(gw8 + (size_t)w * (EE + 1) * 64))[t & 15] = 0u;
        }
        const float* Ws[3] = { W1u + 4096, W1i + 4096, W1t + 4096 };
        bf16x8 bf[3][2];
        #pragma unroll
        for (int w = 0; w < 3; ++w)
            #pragma unroll
            for (int ks = 0; ks < 2; ++ks)
                #pragma unroll
                for (int j = 0; j < 8; ++j)
                    bf[w][ks][j] = (short)f2bf(Ws[w][(ks * 32 + quad * 8 + j) * 64 + cw]);

        const int rowBase = bx * 64;
        #pragma unroll
        for (int i = 0; i < 4; ++i) {
            int idx = t + i * 256;
            int row = idx >> 4, cg = idx & 15;
            int gr = rowBase + row;
            float4 v4 = (gr < EE) ? *(const float4*)(ew + (size_t)gr * 64 + cg * 4)
                                  : make_float4(0.f, 0.f, 0.f, 0.f);
            uint2 pk = { pack2(v4.x, v4.y), pack2(v4.z, v4.w) };
            *(uint2*)&stA[row * 72 + cg * 4] = pk;
        }
        __syncthreads();
        bf16x8 af[4][2];
        #pragma unroll
        for (int m = 0; m < 4; ++m)
            #pragma unroll
            for (int ks = 0; ks < 2; ++ks)
                af[m][ks] = *(const bf16x8*)&stA[(m * 16 + l15) * 72 + ks * 32 + quad * 8];

        #pragma unroll
        for (int w = 0; w < 3; ++w) {
            if (w) __syncthreads();
            f32x4 acc[4];
            #pragma unroll
            for (int m = 0; m < 4; ++m) {
                acc[m].x = 0; acc[m].y = 0; acc[m].z = 0; acc[m].w = 0;
                #pragma unroll
                for (int ks = 0; ks < 2; ++ks)
                    acc[m] = __builtin_amdgcn_mfma_f32_16x16x32_bf16(af[m][ks], bf[w][ks], acc[m], 0, 0, 0);
                #pragma unroll
                for (int r = 0; r < 4; ++r)
                    cS[(m * 16 + quad * 4 + r) * 68 + cw] = acc[m][r];
            }
            __syncthreads();
            unsigned char* outg = gw8 + (size_t)w * (EE + 1) * 64 + 64;  // +1 row shift
            #pragma unroll
            for (int i = 0; i < 2; ++i) {
                int task = t + i * 256;               // 0..511
                int row = task >> 3, seg = task & 7;  // seg: 8 feats
                int gr = rowBase + row;
                if (gr < EE) {
                    float4 a = *(const float4*)&cS[row * 68 + seg * 8];
                    float4 b = *(const float4*)&cS[row * 68 + seg * 8 + 4];
                    uint2 pk = { packfp8x4(a.x, a.y, a.z, a.w),
                                 packfp8x4(b.x, b.y, b.z, b.w) };
                    *(uint2*)(outg + (size_t)gr * 64 + seg * 8) = pk;
                }
            }
        }
    } else {
        // ================= ngemm role =================
        const int yy = bx - ET64;
        const int y = yy / NT64;
        const int rowBase = (yy - y * NT64) * 64;
        if (rowBase == 0 && t < 48)   // zero row 0 of JG table y (192 B)
            ((unsigned*)(JG + (size_t)y * (NN + 1) * 192))[t] = 0u;
        const float* X; const float* Wa; const float* Wb; const float* W2;
        const float* ba; const float* bb; int oa, ob;
        switch (y) {
            case 0:  X = eu; Wa = W1i; ba = bi; oa = 0; Wb = W1t; bb = bt; ob = 1; W2 = W2u; break;
            case 1:  X = ei; Wa = W1u; ba = bu; oa = 2; Wb = W1t; bb = bt; ob = 3; W2 = W2i; break;
            default: X = et; Wa = W1u; ba = bu; oa = 4; Wb = W1i; bb = bi; ob = 5; W2 = W2t; break;
        }
        const float* Ws[3] = { Wa, Wb, W2 };
        const float bias_cw[3] = { ba[cw], bb[cw], 0.f };
        bf16x8 bf[3][2];
        #pragma unroll
        for (int w = 0; w < 3; ++w)
            #pragma unroll
            for (int ks = 0; ks < 2; ++ks)
                #pragma unroll
                for (int j = 0; j < 8; ++j)
                    bf[w][ks][j] = (short)f2bf(Ws[w][(ks * 32 + quad * 8 + j) * 64 + cw]);

        #pragma unroll
        for (int i = 0; i < 4; ++i) {
            int idx = t + i * 256;
            int row = idx >> 4, cg = idx & 15;
            int gr = rowBase + row;
            float4 v4 = (gr < NN) ? *(const float4*)(X + (size_t)gr * 64 + cg * 4)
                                  : make_float4(0.f, 0.f, 0.f, 0.f);
            uint2 pk = { pack2(v4.x, v4.y), pack2(v4.z, v4.w) };
            *(uint2*)&stA[row * 72 + cg * 4] = pk;
        }
        __syncthreads();
        bf16x8 af[4][2];
        #pragma unroll
        for (int m = 0; m < 4; ++m)
            #pragma unroll
            for (int ks = 0; ks < 2; ++ks)
                af[m][ks] = *(const bf16x8*)&stA[(m * 16 + l15) * 72 + ks * 32 + quad * 8];

        #pragma unroll
        for (int w = 0; w < 3; ++w) {
            if (w) __syncthreads();
            f32x4 acc[4];
            #pragma unroll
            for (int m = 0; m < 4; ++m) {
                acc[m].x = 0; acc[m].y = 0; acc[m].z = 0; acc[m].w = 0;
                #pragma unroll
                for (int ks = 0; ks < 2; ++ks)
                    acc[m] = __builtin_amdgcn_mfma_f32_16x16x32_bf16(af[m][ks], bf[w][ks], acc[m], 0, 0, 0);
                #pragma unroll
                for (int r = 0; r < 4; ++r)
                    cS[(m * 16 + quad * 4 + r) * 68 + cw] = acc[m][r] + bias_cw[w];
            }
            __syncthreads();
            #pragma unroll
            for (int i = 0; i < 2; ++i) {
                int task = t + i * 256;
                int row = task >> 3, seg = task & 7;
                int gr = rowBase + row;
                if (gr >= NN) continue;
                float4 a = *(const float4*)&cS[row * 68 + seg * 8];
                float4 b = *(const float4*)&cS[row * 68 + seg * 8 + 4];
                if (w < 2) {
                    int oi = (w == 0) ? oa : ob;
                    uint4 pk = { pkh(a.x, a.y), pkh(a.z, a.w),
                                 pkh(b.x, b.y), pkh(b.z, b.w) };
                    *(uint4*)(preB + ((size_t)oi * NN + gr) * 32 + seg * 4) = pk;
                } else {
                    unsigned char* dst = JG + ((size_t)y * (NN + 1) + gr + 1) * 192;
                    uint2 gj = { packfp8x4(a.x, a.y, a.z, a.w),
                                 packfp8x4(b.x, b.y, b.z, b.w) };
                    *(uint2*)(dst + seg * 8) = gj;
                    uint4 ej = *(const uint4*)&stA[row * 72 + seg * 8];
                    *(uint4*)(dst + 64 + seg * 16) = ej;
                }
            }
        }
    }
}

// ---------------------------------------------------------------------------
// atten1: persistent software-pipelined version.
// Grid (2500, 3): blockIdx.y = g (shared gw8/JG table); blockIdx.x&1 picks
// which of the 2 aggregations using table g. Each block runs exactly 5
// iterations (node stride 5000) with a fully-unrolled 3-stage pipeline:
//   A(it+2): index loads | B(it+1): gw/gj/pre gathers | E(it): ej gathers
//   C(it): logits+softmax+weighted sum+store
// so each iteration's gather latency hides under the previous iteration's
// compute. Weighted ej sum uses f32x2 (v_pk_fma_f32), same per-component
// op order as before (bit-identical numerics).
// ---------------------------------------------------------------------------
__global__ __launch_bounds__(256) void atten1_kernel(
    const unsigned* __restrict__ preB, const unsigned char* __restrict__ gw8,
    const unsigned char* __restrict__ JG,
    const float* __restrict__ vu, const float* __restrict__ vi, const float* __restrict__ vt,
    const int* __restrict__ u_iw_j, const int* __restrict__ u_iw_w,
    const int* __restrict__ u_tw_j, const int* __restrict__ u_tw_w,
    const int* __restrict__ i_uw_j, const int* __restrict__ i_uw_w,
    const int* __restrict__ i_tw_j, const int* __restrict__ i_tw_w,
    const int* __restrict__ t_uw_j, const int* __restrict__ t_uw_w,
    const int* __restrict__ t_iw_j, const int* __restrict__ t_iw_w,
    unsigned* __restrict__ aoB)
{
    const int g = blockIdx.y;
    const int p = blockIdx.x & 1;
    int y; const int* Vj; const int* Vw;
    switch (g * 2 + p) {
        case 0:  y = 2; Vj = i_uw_j; Vw = i_uw_w; break;   // g=0 (user table)
        case 1:  y = 4; Vj = t_uw_j; Vw = t_uw_w; break;
        case 2:  y = 0; Vj = u_iw_j; Vw = u_iw_w; break;   // g=1 (item table)
        case 3:  y = 5; Vj = t_iw_j; Vw = t_iw_w; break;
        case 4:  y = 1; Vj = u_tw_j; Vw = u_tw_w; break;   // g=2 (tag table)
        default: y = 3; Vj = i_tw_j; Vw = i_tw_w; break;
    }
    const float* v = (g == 0) ? vu : (g == 1) ? vi : vt;
    const unsigned* pre = preB + (size_t)y * NN * 32;
    const unsigned char* gw = gw8 + (size_t)g * (EE + 1) * 64;
    const unsigned char* jg = JG + (size_t)g * (NN + 1) * 192;
    unsigned*            out = aoB + (size_t)y * NN * 32;

    const int lane = threadIdx.x & 63;
    const int q = lane >> 4, r = lane & 15;
    // node for iteration it: n0 + it*5000  (exact partition of [0,25000))
    const int n0 = (blockIdx.x >> 1) * 4 + (threadIdx.x >> 6);

    const float4 v4 = *(const float4*)(v + r * 4);
    const h2 v01h = __builtin_amdgcn_cvt_pkrtz(v4.x, v4.y);
    const h2 v23h = __builtin_amdgcn_cvt_pkrtz(v4.z, v4.w);

    // pipeline slots (fully unrolled loop -> all indices compile-time)
    int4 wi[5], ji[5];
    uint2 prep[5];
    unsigned gwv[5][4], gjv[5][4];
    uint2 ejv[5][4];

    #define A_STAGE(IT) {                                                     \
        int nn = n0 + (IT) * 5000;                                            \
        wi[IT] = *(const int4*)(Vw + (size_t)nn * 16 + q * 4);                \
        ji[IT] = *(const int4*)(Vj + (size_t)nn * 16 + q * 4);                \
    }
    #define B_STAGE(IT) {                                                     \
        int nn = n0 + (IT) * 5000;                                            \
        prep[IT] = *(const uint2*)(pre + (size_t)nn * 32 + 2 * r);            \
        gwv[IT][0] = *(const unsigned*)(gw + (size_t)wi[IT].x * 64 + r * 4);  \
        gwv[IT][1] = *(const unsigned*)(gw + (size_t)wi[IT].y * 64 + r * 4);  \
        gwv[IT][2] = *(const unsigned*)(gw + (size_t)wi[IT].z * 64 + r * 4);  \
        gwv[IT][3] = *(const unsigned*)(gw + (size_t)wi[IT].w * 64 + r * 4);  \
        gjv[IT][0] = *(const unsigned*)(jg + (size_t)ji[IT].x * 192 + r * 4); \
        gjv[IT][1] = *(const unsigned*)(jg + (size_t)ji[IT].y * 192 + r * 4); \
        gjv[IT][2] = *(const unsigned*)(jg + (size_t)ji[IT].z * 192 + r * 4); \
        gjv[IT][3] = *(const unsigned*)(jg + (size_t)ji[IT].w * 192 + r * 4); \
    }
    #define E_STAGE(IT) {                                                     \
        ejv[IT][0] = *(const uint2*)(jg + (size_t)ji[IT].x * 192 + 64 + r * 8); \
        ejv[IT][1] = *(const uint2*)(jg + (size_t)ji[IT].y * 192 + 64 + r * 8); \
        ejv[IT][2] = *(const uint2*)(jg + (size_t)ji[IT].z * 192 + 64 + r * 8); \
        ejv[IT][3] = *(const uint2*)(jg + (size_t)ji[IT].w * 192 + 64 + r * 8); \
    }

    // prologue
    A_STAGE(0);
    A_STAGE(1);
    B_STAGE(0);

    #pragma unroll
    for (int it = 0; it < 5; ++it) {
        // issue ej gathers for this iteration (consumed after softmax)
        E_STAGE(it);
        // keep the pipeline primed
        if (it + 1 < 5) B_STAGE(it + 1);
        if (it + 2 < 5) A_STAGE(it + 2);

        // ---- C(it): compute ----
        const h2 pre01 = __builtin_bit_cast(h2, prep[it].x);
        const h2 pre23 = __builtin_bit_cast(h2, prep[it].y);

        float xk[4];
        #pragma unroll
        for (int i = 0; i < 4; ++i) {
            h2 g01 = fp8toh<false>(gwv[it][i]);
            h2 g23 = fp8toh<true>(gwv[it][i]);
            h2 j01 = fp8toh<false>(gjv[it][i]);
            h2 j23 = fp8toh<true>(gjv[it][i]);
            h2 z01 = hmax0(pre01 + g01 + j01);
            h2 z23 = hmax0(pre23 + g23 + j23);
            float x = hdot(z01, v01h, 0.f);
            x = hdot(z23, v23h, x);
            x += __shfl_xor(x, 1, 64);
            x += __shfl_xor(x, 2, 64);
            x += __shfl_xor(x, 4, 64);
            x += __shfl_xor(x, 8, 64);
            xk[i] = x;
        }
        // softmax over 16 k (4 local regs x 4 q-groups)
        float m = fmaxf(fmaxf(xk[0], xk[1]), fmaxf(xk[2], xk[3]));
        m = fmaxf(m, __shfl_xor(m, 16, 64));
        m = fmaxf(m, __shfl_xor(m, 32, 64));
        float e0 = __expf(xk[0] - m), e1 = __expf(xk[1] - m);
        float e2 = __expf(xk[2] - m), e3 = __expf(xk[3] - m);
        float s = (e0 + e1) + (e2 + e3);
        s += __shfl_xor(s, 16, 64);
        s += __shfl_xor(s, 32, 64);
        const float inv = 1.f / s;

        // weighted ej sum (f32x2 -> v_pk_fma_f32; same per-component order)
        const float wgt[4] = { e0 * inv, e1 * inv, e2 * inv, e3 * inv };
        f32x2 A01; A01.x = 0.f; A01.y = 0.f;
        f32x2 A23; A23.x = 0.f; A23.y = 0.f;
        #pragma unroll
        for (int i = 0; i < 4; ++i) {
            f32x2 w2; w2.x = wgt[i]; w2.y = wgt[i];
            f32x2 e01; e01.x = bflo(ejv[it][i].x); e01.y = bfhi(ejv[it][i].x);
            f32x2 e23; e23.x = bflo(ejv[it][i].y); e23.y = bfhi(ejv[it][i].y);
            A01 = e01 * w2 + A01;
            A23 = e23 * w2 + A23;
        }
        float a0 = A01.x, a1 = A01.y, a2 = A23.x, a3 = A23.y;
        a0 += __shfl_xor(a0, 16, 64); a0 += __shfl_xor(a0, 32, 64);
        a1 += __shfl_xor(a1, 16, 64); a1 += __shfl_xor(a1, 32, 64);
        a2 += __shfl_xor(a2, 16, 64); a2 += __shfl_xor(a2, 32, 64);
        a3 += __shfl_xor(a3, 16, 64); a3 += __shfl_xor(a3, 32, 64);
        if (q == 0) {
            int nn = n0 + it * 5000;
            uint2 pk = { pack2(a0, a1), pack2(a2, a3) };
            *(uint2*)(out + (size_t)nn * 32 + 2 * r) = pk;
        }
    }
    #undef A_STAGE
    #undef B_STAGE
    #undef E_STAGE
}

// ---------------------------------------------------------------------------
// tail: atten2 + convs + final linear, all MFMA (16x16x32 bf16). (unchanged)
// ---------------------------------------------------------------------------
__global__ __launch_bounds__(256, 3) void tail_kernel(
    const float* __restrict__ eu, const float* __restrict__ ei, const float* __restrict__ et,
    const unsigned* __restrict__ aoB,
    const float* __restrict__ U, const float* __restrict__ q, const float* __restrict__ p,
    const float* __restrict__ Wbit, const float* __restrict__ Wv1,
    const float* __restrict__ Wv2, const float* __restrict__ Wv3,
    const float* __restrict__ Wf, const float* __restrict__ bfv,
    float* __restrict__ out)
{
    __shared__ __align__(16) unsigned short uitA[48 * 72];
    __shared__ __align__(16) unsigned short eNA[48 * 72];
    __shared__ __align__(16) unsigned short wcf[6 * 64 * 8];
    __shared__ __align__(16) unsigned short c_sh[16 * 584];
    __shared__ float G_sh[48 * 52];
    __shared__ float xpart[4 * 48];
    __shared__ float bcoef[16 * 4];

    const int t = threadIdx.x;
    const int lane = t & 63;
    const int wv = t >> 6;
    const int l15 = lane & 15;
    const int quad = lane >> 4;
    const int type = blockIdx.y;
    const float* xf = (type == 0) ? eu : (type == 1) ? ei : et;
    const int cw = wv * 16 + l15;
    const float qv = q[cw], pv = p[cw], bfb = bfv[cw];

    float wb[8][3];
    #pragma unroll
    for (int c = 0; c < 8; ++c)
        #pragma unroll
        for (int s = 0; s < 3; ++s) wb[c][s] = Wbit[c * 3 + s];

    bf16x8 ufrag[2];
    #pragma unroll
    for (int ks = 0; ks < 2; ++ks)
        #pragma unroll
        for (int j = 0; j < 8; ++j) {
            int f = ks * 32 + quad * 8 + j;
            ufrag[ks][j] = (short)f2bf(U[f * 64 + cw]);
        }
    bf16x8 wff[18];
    #pragma unroll
    for (int ks = 0; ks < 18; ++ks)
        #pragma unroll
        for (int j = 0; j < 8; ++j) {
            int k = ks * 32 + quad * 8 + j;
            float w = (k < 560) ? Wf[(size_t)k * 64 + cw] : 0.f;
            wff[ks][j] = (short)f2bf(w);
        }
    for (int slot = t; slot < 384; slot += 256) {
        int fi = slot >> 6, l = slot & 63;
        int nt_ = fi >> 1, ks = fi & 1;
        int r = nt_ * 16 + (l & 15);
        unsigned short vals[8];
        #pragma unroll
        for (int j = 0; j < 8; ++j) {
            int f = ks * 32 + (l >> 4) * 8 + j;
            float wv_;
            if (r < 8)       wv_ = Wv1[r * 64 + f];
            else if (r < 24) { int u = r - 8;  wv_ = Wv2[(u >> 1) * 128 + (u & 1) * 64 + f]; }
            else             { int u = r - 24; wv_ = Wv3[(u / 3) * 192 + (u % 3) * 64 + f]; }
            vals[j] = f2bf(wv_);
        }
        uint4 pk = { (unsigned)vals[0] | ((unsigned)vals[1] << 16),
                     (unsigned)vals[2] | ((unsigned)vals[3] << 16),
                     (unsigned)vals[4] | ((unsigned)vals[5] << 16),
                     (unsigned)vals[6] | ((unsigned)vals[7] << 16) };
        *(uint4*)&wcf[slot * 8] = pk;
    }

    for (int tile = blockIdx.x; tile < NT; tile += gridDim.x) {
        const int nodeBase = tile * 16;
        __syncthreads();
        #pragma unroll
        for (int i = 0; i < 3; ++i) {
            int idx = t + i * 256;
            int row = idx >> 4, cg = idx & 15;
            int nl = row / 3, s = row - nl * 3;
            int n = nodeBase + nl;
            uint2 pk;
            if (s == type) {
                float4 v4 = (n < NN) ? *(const float4*)(xf + (size_t)n * 64 + cg * 4)
                                     : make_float4(0.f, 0.f, 0.f, 0.f);
                pk.x = pack2(v4.x, v4.y); pk.y = pack2(v4.z, v4.w);
            } else {
                int aoidx = (type == 0) ? (s - 1)
                          : (type == 1) ? ((s == 0) ? 2 : 3)
                                        : ((s == 0) ? 4 : 5);
                pk = (n < NN) ? *(const uint2*)(aoB + ((size_t)aoidx * NN + n) * 32 + cg * 2)
                              : make_uint2(0u, 0u);
            }
            *(uint2*)&uitA[row * 72 + cg * 4] = pk;
        }
        __syncthreads();
        {
            f32x4 av[3];
            #pragma unroll
            for (int mt = 0; mt < 3; ++mt) { av[mt].x = 0; av[mt].y = 0; av[mt].z = 0; av[mt].w = 0; }
            #pragma unroll
            for (int mt = 0; mt < 3; ++mt)
                #pragma unroll
                for (int ks = 0; ks < 2; ++ks) {
                    bf16x8 a = *(const bf16x8*)&uitA[(mt * 16 + l15) * 72 + ks * 32 + quad * 8];
                    av[mt] = __builtin_amdgcn_mfma_f32_16x16x32_bf16(a, ufrag[ks], av[mt], 0, 0, 0);
                }
            #pragma unroll
            for (int mt = 0; mt < 3; ++mt)
                #pragma unroll
                for (int r = 0; r < 4; ++r) {
                    float val = fmaxf(av[mt][r] + qv, 0.f) * pv;
                    val += __shfl_xor(val, 1, 64); val += __shfl_xor(val, 2, 64);
                    val += __shfl_xor(val, 4, 64); val += __shfl_xor(val, 8, 64);
                    if (l15 == 0) xpart[wv * 48 + mt * 16 + quad * 4 + r] = val;
                }
        }
        __syncthreads();
        if (t < 16) {
            float xv[3];
            #pragma unroll
            for (int s = 0; s < 3; ++s)
                xv[s] = xpart[t * 3 + s] + xpart[48 + t * 3 + s]
                      + xpart[96 + t * 3 + s] + xpart[144 + t * 3 + s];
            float mm = fmaxf(xv[0], fmaxf(xv[1], xv[2]));
            float e0 = __expf(xv[0] - mm), e1 = __expf(xv[1] - mm), e2 = __expf(xv[2] - mm);
            float inv = 1.f / (e0 + e1 + e2);
            bcoef[t * 4 + 0] = e0 * inv; bcoef[t * 4 + 1] = e1 * inv; bcoef[t * 4 + 2] = e2 * inv;
        }
        __syncthreads();
        #pragma unroll
        for (int i = 0; i < 2; ++i) {
            int task = t + i * 256;
            int nl = task >> 5, fp = task & 31;
            float b0 = bcoef[nl * 4], b1 = bcoef[nl * 4 + 1], b2 = bcoef[nl * 4 + 2];
            unsigned u0 = *(const unsigned*)&uitA[(nl * 3 + 0) * 72 + fp * 2];
            unsigned u1 = *(const unsigned*)&uitA[(nl * 3 + 1) * 72 + fp * 2];
            unsigned u2 = *(const unsigned*)&uitA[(nl * 3 + 2) * 72 + fp * 2];
            float e0l = b0 * bflo(u0), e0h = b0 * bfhi(u0);
            float e1l = b1 * bflo(u1), e1h = b1 * bfhi(u1);
            float e2l = b2 * bflo(u2), e2h = b2 * bfhi(u2);
            *(unsigned*)&eNA[(nl * 3 + 0) * 72 + fp * 2] = pack2(e0l, e0h);
            *(unsigned*)&eNA[(nl * 3 + 1) * 72 + fp * 2] = pack2(e1l, e1h);
            *(unsigned*)&eNA[(nl * 3 + 2) * 72 + fp * 2] = pack2(e2l, e2h);
            #pragma unroll
            for (int c = 0; c < 8; ++c) {
                float lo = fmaxf(wb[c][0] * e0l + wb[c][1] * e1l + wb[c][2] * e2l, 0.f);
                float hi = fmaxf(wb[c][0] * e0h + wb[c][1] * e1h + wb[c][2] * e2h, 0.f);
                *(unsigned*)&c_sh[nl * 584 + c * 64 + fp * 2] = pack2(lo, hi);
            }
        }
        __syncthreads();
        #pragma unroll
        for (int pi = 0; pi < 3; ++pi) {
            int pr = wv + pi * 4;
            if (pr < 9) {
                int mm = pr / 3, nn_ = pr - mm * 3;
                f32x4 g; g.x = 0; g.y = 0; g.z = 0; g.w = 0;
                #pragma unroll
                for (int ks = 0; ks < 2; ++ks) {
                    bf16x8 a = *(const bf16x8*)&eNA[(mm * 16 + l15) * 72 + ks * 32 + quad * 8];
                    bf16x8 b = *(const bf16x8*)&wcf[((nn_ * 2 + ks) * 64 + lane) * 8];
                    g = __builtin_amdgcn_mfma_f32_16x16x32_bf16(a, b, g, 0, 0, 0);
                }
                #pragma unroll
                for (int r = 0; r < 4; ++r)
                    G_sh[(mm * 16 + quad * 4 + r) * 52 + nn_ * 16 + l15] = g[r];
            }
        }
        __syncthreads();
        #pragma unroll
        for (int i = 0; i < 4; ++i) {
            int task = t + i * 256;
            int vvv = task >> 4, nl = task & 15;
            unsigned short res = 0;
            if (vvv < 24) {
                int c = vvv / 3, s = vvv - c * 3;
                res = f2bf(fmaxf(G_sh[(nl * 3 + s) * 52 + c], 0.f));
            } else if (vvv < 40) {
                int u = vvv - 24, c = u >> 1, s = u & 1;
                float val = G_sh[(nl * 3 + s) * 52 + 8 + 2 * c]
                          + G_sh[(nl * 3 + s + 1) * 52 + 8 + 2 * c + 1];
                res = f2bf(fmaxf(val, 0.f));
            } else if (vvv < 48) {
                int c = vvv - 40;
                float val = G_sh[(nl * 3 + 0) * 52 + 24 + 3 * c]
                          + G_sh[(nl * 3 + 1) * 52 + 24 + 3 * c + 1]
                          + G_sh[(nl * 3 + 2) * 52 + 24 + 3 * c + 2];
                res = f2bf(fmaxf(val, 0.f));
            }
            c_sh[nl * 584 + 512 + vvv] = res;
        }
        __syncthreads();
        {
            f32x4 acc; acc.x = 0; acc.y = 0; acc.z = 0; acc.w = 0;
            const unsigned short* ap = &c_sh[l15 * 584 + quad * 8];
            #pragma unroll
            for (int ks = 0; ks < 18; ++ks) {
                bf16x8 a = *(const bf16x8*)(ap + ks * 32);
                acc = __builtin_amdgcn_mfma_f32_16x16x32_bf16(a, wff[ks], acc, 0, 0, 0);
            }
            float* outT = out + (size_t)type * NN * 64;
            #pragma unroll
            for (int r = 0; r < 4; ++r) {
                int node = nodeBase + quad * 4 + r;
                if (node < NN) outT[(size_t)node * 64 + cw] = fmaxf(acc[r] + bfb, 0.f);
            }
        }
    }
}

// ---------------------------------------------------------------------------
extern "C" void kernel_launch(void* const* d_in, const int* in_sizes, int n_in,
                              void* d_out, int out_size, void* d_ws, size_t ws_size,
                              hipStream_t stream)
{
    const float* eu = (const float*)d_in[0];
    const float* ei = (const float*)d_in[1];
    const float* et = (const float*)d_in[2];
    const float* ew = (const float*)d_in[3];
    const int* u_iw_j = (const int*)d_in[4];
    const int* u_iw_w = (const int*)d_in[5];
    const int* u_tw_j = (const int*)d_in[6];
    const int* u_tw_w = (const int*)d_in[7];
    const int* i_uw_j = (const int*)d_in[8];
    const int* i_uw_w = (const int*)d_in[9];
    const int* i_tw_j = (const int*)d_in[10];
    const int* i_tw_w = (const int*)d_in[11];
    const int* t_uw_j = (const int*)d_in[12];
    const int* t_uw_w = (const int*)d_in[13];
    const int* t_iw_j = (const int*)d_in[14];
    const int* t_iw_w = (const int*)d_in[15];
    const float* W1_user = (const float*)d_in[16];
    const float* W2_user = (const float*)d_in[17];
    const float* b_user  = (const float*)d_in[18];
    const float* v_user  = (const float*)d_in[19];
    const float* W1_item = (const float*)d_in[20];
    const float* W2_item = (const float*)d_in[21];
    const float* b_item  = (const float*)d_in[22];
    const float* v_item  = (const float*)d_in[23];
    const float* W1_tag  = (const float*)d_in[24];
    const float* W2_tag  = (const float*)d_in[25];
    const float* b_tag   = (const float*)d_in[26];
    const float* v_tag   = (const float*)d_in[27];
    const float* U    = (const float*)d_in[28];
    const float* q    = (const float*)d_in[29];
    const float* p    = (const float*)d_in[30];
    const float* Wbit = (const float*)d_in[31];
    const float* Wv1  = (const float*)d_in[32];
    const float* Wv2  = (const float*)d_in[33];
    const float* Wv3  = (const float*)d_in[34];
    const float* Wf   = (const float*)d_in[35];
    const float* bfv  = (const float*)d_in[36];
    float* out = (float*)d_out;

    // ---- workspace (~110 MB):
    // gw8: 3*(E+1)*64 B | preB: 6*N*128 B | JG: 3*(N+1)*192 B | aoB: 6*N*128 B
    unsigned char* gw8 = (unsigned char*)d_ws;
    unsigned* preB = (unsigned*)(gw8 + (size_t)3 * (EE + 1) * 64);
    unsigned char* JG = (unsigned char*)(preB + (size_t)6 * NN * 32);
    unsigned* aoB = (unsigned*)(JG + (size_t)3 * (NN + 1) * 192);

    const dim3 blk(256);

    head_kernel<<<ET64 + 3 * NT64, blk, 0, stream>>>(
        ew, eu, ei, et,
        W1_user, W1_item, W1_tag, W2_user, W2_item, W2_tag,
        b_user, b_item, b_tag, gw8, preB, JG);

    atten1_kernel<<<dim3(2500, 3), blk, 0, stream>>>(
        preB, gw8, JG, v_user, v_item, v_tag,
        u_iw_j, u_iw_w, u_tw_j, u_tw_w, i_uw_j, i_uw_w,
        i_tw_j, i_tw_w, t_uw_j, t_uw_w, t_iw_j, t_iw_w, aoB);

    tail_kernel<<<dim3(256, 3), blk, 0, stream>>>(
        eu, ei, et, aoB,
        U, q, p, Wbit, Wv1, Wv2, Wv3, Wf, bfv, out);
}

// Round 4
// 389.737 us; speedup vs baseline: 1.0243x; 1.0243x over previous
//
#include <hip/hip_runtime.h>
#include <math.h>

#define NN 25000
#define EE 300000
#define NT 1563          // ceil(25000/16)   (tail tiles)
#define ET128 2344       // ceil(300000/128) (egemm blocks, 2 tiles each)
#define NT128 196        // ceil(25000/128)  (ngemm blocks per y, 2 tiles each)

typedef __attribute__((ext_vector_type(8))) short bf16x8;
typedef __attribute__((ext_vector_type(4))) float f32x4;
typedef __attribute__((ext_vector_type(2))) float f32x2;
typedef __attribute__((ext_vector_type(2))) __fp16 h2;

__device__ __forceinline__ unsigned short f2bf(float f) {
    union { float f; unsigned u; } a; a.f = f;
    unsigned r = (a.u + 0x7fffu + ((a.u >> 16) & 1u)) >> 16;   // RNE
    return (unsigned short)r;
}
__device__ __forceinline__ unsigned pack2(float lo, float hi) {
    return (unsigned)f2bf(lo) | ((unsigned)f2bf(hi) << 16);
}
__device__ __forceinline__ float bflo(unsigned p) {
    union { unsigned u; float f; } a; a.u = p << 16; return a.f;
}
__device__ __forceinline__ float bfhi(unsigned p) {
    union { unsigned u; float f; } a; a.u = p & 0xffff0000u; return a.f;
}
// pack 4 floats -> 4 fp8(e4m3 OCP) in one uint
__device__ __forceinline__ unsigned packfp8x4(float a, float b, float c, float d) {
    int v = __builtin_amdgcn_cvt_pk_fp8_f32(a, b, 0, 0);
    v = __builtin_amdgcn_cvt_pk_fp8_f32(c, d, v, 1);
    return (unsigned)v;
}
// pack 2 floats -> packed f16 pair (uint)
__device__ __forceinline__ unsigned pkh(float lo, float hi) {
    h2 r = __builtin_amdgcn_cvt_pkrtz(lo, hi);
    return __builtin_bit_cast(unsigned, r);
}
// 2 fp8 (word sel = template const) -> half2
template<bool HI>
__device__ __forceinline__ h2 fp8toh(unsigned v) {
#if __has_builtin(__builtin_amdgcn_cvt_scalef32_pk_f16_fp8)
    return __builtin_amdgcn_cvt_scalef32_pk_f16_fp8((int)v, 1.0f, HI);
#else
    f32x2 f = __builtin_amdgcn_cvt_pk_f32_fp8((int)v, HI);
    return __builtin_amdgcn_cvt_pkrtz(f.x, f.y);
#endif
}
// half2 dot with f32 accumulate
__device__ __forceinline__ float hdot(h2 a, h2 b, float c) {
#if __has_builtin(__builtin_amdgcn_fdot2)
    return __builtin_amdgcn_fdot2(a, b, c, false);
#else
    return c + (float)a[0] * (float)b[0] + (float)a[1] * (float)b[1];
#endif
}
__device__ __forceinline__ h2 hmax0(h2 a) {
    h2 z; z[0] = (__fp16)0.f; z[1] = (__fp16)0.f;
#if __has_builtin(__builtin_elementwise_max)
    return __builtin_elementwise_max(a, z);
#else
    h2 r;
    r[0] = a[0] > z[0] ? a[0] : z[0];
    r[1] = a[1] > z[1] ? a[1] : z[1];
    return r;
#endif
}

// ---------------------------------------------------------------------------
// head: fused egemm + ngemm. 128-row blocks (2 tiles of 64), weights loaded
// once per block; all 24 MFMAs issued up-front into acc[3][4]; the fp8/f16
// transpose uses a DOUBLE-BUFFERED cS (cSa/cSb) so each barrier interval
// overlaps {store of w} with {LDS-write of w+1}: 4 barriers/tile vs 7.
//  egemm (blocks [0,ET128)): gw8[g][1+e] = fp8( ew[e] @ W1g[64:128,:] ); row0=0
//  ngemm: per source X in {eu,ei,et}:
//    preB = f16(X@Wa + ba), f16(X@Wb + bb)
//    JG[y][1+n] = [ fp8(X@W2) 64B | bf16(X) 128B ] (192 B rows); row 0 = 0
// ---------------------------------------------------------------------------
__global__ __launch_bounds__(256) void head_kernel(
    const float* __restrict__ ew,
    const float* __restrict__ eu, const float* __restrict__ ei, const float* __restrict__ et,
    const float* __restrict__ W1u, const float* __restrict__ W1i, const float* __restrict__ W1t,
    const float* __restrict__ W2u, const float* __restrict__ W2i, const float* __restrict__ W2t,
    const float* __restrict__ bu, const float* __restrict__ bi, const float* __restrict__ bt,
    unsigned char* __restrict__ gw8, unsigned* __restrict__ preB,
    unsigned char* __restrict__ JG)
{
    __shared__ __align__(16) unsigned short stA[64 * 72];
    __shared__ __align__(16) float cSa[64 * 68];
    __shared__ __align__(16) float cSb[64 * 68];
    const int t = threadIdx.x;
    const int lane = t & 63, wv = t >> 6;
    const int l15 = lane & 15, quad = lane >> 4;
    const int cw = wv * 16 + l15;                 // this wave's output col
    const int bx = blockIdx.x;

    if (bx < ET128) {
        // ================= egemm role =================
        if (bx == 0 && t < 48) {   // zero row 0 of the 3 gw8 tables (64 B each)
            int w = t >> 4;
            ((unsigned*)(gw8 + (size_t)w * (EE + 1) * 64))[t & 15] = 0u;
        }
        const float* Ws[3] = { W1u + 4096, W1i + 4096, W1t + 4096 };
        bf16x8 bf[3][2];
        #pragma unroll
        for (int w = 0; w < 3; ++w)
            #pragma unroll
            for (int ks = 0; ks < 2; ++ks)
                #pragma unroll
                for (int j = 0; j < 8; ++j)
                    bf[w][ks][j] = (short)f2bf(Ws[w][(ks * 32 + quad * 8 + j) * 64 + cw]);

        #pragma unroll
        for (int tile = 0; tile < 2; ++tile) {
            const int rowBase = bx * 128 + tile * 64;
            // ---- stage 64 rows of ew as bf16 ----
            #pragma unroll
            for (int i = 0; i < 4; ++i) {
                int idx = t + i * 256;
                int row = idx >> 4, cg = idx & 15;
                int gr = rowBase + row;
                float4 v4 = (gr < EE) ? *(const float4*)(ew + (size_t)gr * 64 + cg * 4)
                                      : make_float4(0.f, 0.f, 0.f, 0.f);
                uint2 pk = { pack2(v4.x, v4.y), pack2(v4.z, v4.w) };
                *(uint2*)&stA[row * 72 + cg * 4] = pk;
            }
            __syncthreads();
            bf16x8 af[4][2];
            #pragma unroll
            for (int m = 0; m < 4; ++m)
                #pragma unroll
                for (int ks = 0; ks < 2; ++ks)
                    af[m][ks] = *(const bf16x8*)&stA[(m * 16 + l15) * 72 + ks * 32 + quad * 8];

            // ---- all 24 MFMAs up-front ----
            f32x4 acc[3][4];
            #pragma unroll
            for (int w = 0; w < 3; ++w)
                #pragma unroll
                for (int m = 0; m < 4; ++m) {
                    acc[w][m].x = 0; acc[w][m].y = 0; acc[w][m].z = 0; acc[w][m].w = 0;
                    #pragma unroll
                    for (int ks = 0; ks < 2; ++ks)
                        acc[w][m] = __builtin_amdgcn_mfma_f32_16x16x32_bf16(af[m][ks], bf[w][ks], acc[w][m], 0, 0, 0);
                }

            // ---- transpose+store pipeline: cSa(w0) | {st w0, cSb(w1)} | {st w1, cSa(w2)} | st w2
            #define EG_WRITE(BUF, W) {                                               \
                _Pragma("unroll")                                                    \
                for (int m = 0; m < 4; ++m)                                          \
                    _Pragma("unroll")                                                \
                    for (int r = 0; r < 4; ++r)                                      \
                        BUF[(m * 16 + quad * 4 + r) * 68 + cw] = acc[W][m][r];       \
            }
            #define EG_STORE(BUF, W) {                                               \
                unsigned char* outg = gw8 + (size_t)(W) * (EE + 1) * 64 + 64;        \
                _Pragma("unroll")                                                    \
                for (int i = 0; i < 2; ++i) {                                        \
                    int task = t + i * 256;                                          \
                    int row = task >> 3, seg = task & 7;                             \
                    int gr = rowBase + row;                                          \
                    if (gr < EE) {                                                   \
                        float4 a = *(const float4*)&BUF[row * 68 + seg * 8];         \
                        float4 b = *(const float4*)&BUF[row * 68 + seg * 8 + 4];     \
                        uint2 pk = { packfp8x4(a.x, a.y, a.z, a.w),                  \
                                     packfp8x4(b.x, b.y, b.z, b.w) };                \
                        *(uint2*)(outg + (size_t)gr * 64 + seg * 8) = pk;            \
                    }                                                                \
                }                                                                    \
            }
            EG_WRITE(cSa, 0);
            __syncthreads();
            EG_STORE(cSa, 0);
            EG_WRITE(cSb, 1);
            __syncthreads();
            EG_STORE(cSb, 1);
            EG_WRITE(cSa, 2);
            __syncthreads();
            EG_STORE(cSa, 2);
            #undef EG_WRITE
            #undef EG_STORE
        }
    } else {
        // ================= ngemm role =================
        const int yy = bx - ET128;
        const int y = yy / NT128;
        const int rowBase0 = (yy - y * NT128) * 128;
        if (rowBase0 == 0 && t < 48)   // zero row 0 of JG table y (192 B)
            ((unsigned*)(JG + (size_t)y * (NN + 1) * 192))[t] = 0u;
        const float* X; const float* Wa; const float* Wb; const float* W2;
        const float* ba; const float* bb; int oa, ob;
        switch (y) {
            case 0:  X = eu; Wa = W1i; ba = bi; oa = 0; Wb = W1t; bb = bt; ob = 1; W2 = W2u; break;
            case 1:  X = ei; Wa = W1u; ba = bu; oa = 2; Wb = W1t; bb = bt; ob = 3; W2 = W2i; break;
            default: X = et; Wa = W1u; ba = bu; oa = 4; Wb = W1i; bb = bi; ob = 5; W2 = W2t; break;
        }
        const float* Ws[3] = { Wa, Wb, W2 };
        const float bias_cw[3] = { ba[cw], bb[cw], 0.f };
        bf16x8 bf[3][2];
        #pragma unroll
        for (int w = 0; w < 3; ++w)
            #pragma unroll
            for (int ks = 0; ks < 2; ++ks)
                #pragma unroll
                for (int j = 0; j < 8; ++j)
                    bf[w][ks][j] = (short)f2bf(Ws[w][(ks * 32 + quad * 8 + j) * 64 + cw]);

        #pragma unroll
        for (int tile = 0; tile < 2; ++tile) {
            const int rowBase = rowBase0 + tile * 64;
            if (tile) __syncthreads();   // prior tile's w2 phase reads stA
            #pragma unroll
            for (int i = 0; i < 4; ++i) {
                int idx = t + i * 256;
                int row = idx >> 4, cg = idx & 15;
                int gr = rowBase + row;
                float4 v4 = (gr < NN) ? *(const float4*)(X + (size_t)gr * 64 + cg * 4)
                                      : make_float4(0.f, 0.f, 0.f, 0.f);
                uint2 pk = { pack2(v4.x, v4.y), pack2(v4.z, v4.w) };
                *(uint2*)&stA[row * 72 + cg * 4] = pk;
            }
            __syncthreads();
            bf16x8 af[4][2];
            #pragma unroll
            for (int m = 0; m < 4; ++m)
                #pragma unroll
                for (int ks = 0; ks < 2; ++ks)
                    af[m][ks] = *(const bf16x8*)&stA[(m * 16 + l15) * 72 + ks * 32 + quad * 8];

            f32x4 acc[3][4];
            #pragma unroll
            for (int w = 0; w < 3; ++w)
                #pragma unroll
                for (int m = 0; m < 4; ++m) {
                    acc[w][m].x = 0; acc[w][m].y = 0; acc[w][m].z = 0; acc[w][m].w = 0;
                    #pragma unroll
                    for (int ks = 0; ks < 2; ++ks)
                        acc[w][m] = __builtin_amdgcn_mfma_f32_16x16x32_bf16(af[m][ks], bf[w][ks], acc[w][m], 0, 0, 0);
                }

            #define NG_WRITE(BUF, W) {                                                     \
                _Pragma("unroll")                                                          \
                for (int m = 0; m < 4; ++m)                                                \
                    _Pragma("unroll")                                                      \
                    for (int r = 0; r < 4; ++r)                                            \
                        BUF[(m * 16 + quad * 4 + r) * 68 + cw] = acc[W][m][r] + bias_cw[W];\
            }
            // w<2 -> preB f16 pairs; w==2 -> JG (fp8 + bf16 ej copy from stA)
            #define NG_STORE(BUF, W) {                                                     \
                _Pragma("unroll")                                                          \
                for (int i = 0; i < 2; ++i) {                                              \
                    int task = t + i * 256;                                                \
                    int row = task >> 3, seg = task & 7;                                   \
                    int gr = rowBase + row;                                                \
                    if (gr < NN) {                                                         \
                        float4 a = *(const float4*)&BUF[row * 68 + seg * 8];               \
                        float4 b = *(const float4*)&BUF[row * 68 + seg * 8 + 4];           \
                        if ((W) < 2) {                                                     \
                            int oi = ((W) == 0) ? oa : ob;                                 \
                            uint4 pk = { pkh(a.x, a.y), pkh(a.z, a.w),                     \
                                         pkh(b.x, b.y), pkh(b.z, b.w) };                   \
                            *(uint4*)(preB + ((size_t)oi * NN + gr) * 32 + seg * 4) = pk;  \
                        } else {                                                           \
                            unsigned char* dst = JG + ((size_t)y * (NN + 1) + gr + 1) * 192;\
                            uint2 gj = { packfp8x4(a.x, a.y, a.z, a.w),                    \
                                         packfp8x4(b.x, b.y, b.z, b.w) };                  \
                            *(uint2*)(dst + seg * 8) = gj;                                 \
                            uint4 ej = *(const uint4*)&stA[row * 72 + seg * 8];            \
                            *(uint4*)(dst + 64 + seg * 16) = ej;                           \
                        }                                                                  \
                    }                                                                      \
                }                                                                          \
            }
            NG_WRITE(cSa, 0);
            __syncthreads();
            NG_STORE(cSa, 0);
            NG_WRITE(cSb, 1);
            __syncthreads();
            NG_STORE(cSb, 1);
            NG_WRITE(cSa, 2);
            __syncthreads();
            NG_STORE(cSa, 2);
            #undef NG_WRITE
            #undef NG_STORE
        }
    }
}

// ---------------------------------------------------------------------------
// atten1: r2 form (best measured: 92.5us). Grid (12500, 3): blockIdx.y = g
// (shared gw8/JG table); blockIdx.x&1 picks which of the 2 aggregations using
// table g (temporal co-residency). Logit MLP in packed f16; all gathers
// issued up-front; weighted ej sum via f32x2 (v_pk_fma_f32).
// Pinned at ~3.67 TB/s L2-miss BW across 3 structural variants -> treated as
// the random-gather roofline for this layout (4 lines / neighbor).
// ---------------------------------------------------------------------------
__global__ __launch_bounds__(256) void atten1_kernel(
    const unsigned* __restrict__ preB, const unsigned char* __restrict__ gw8,
    const unsigned char* __restrict__ JG,
    const float* __restrict__ vu, const float* __restrict__ vi, const float* __restrict__ vt,
    const int* __restrict__ u_iw_j, const int* __restrict__ u_iw_w,
    const int* __restrict__ u_tw_j, const int* __restrict__ u_tw_w,
    const int* __restrict__ i_uw_j, const int* __restrict__ i_uw_w,
    const int* __restrict__ i_tw_j, const int* __restrict__ i_tw_w,
    const int* __restrict__ t_uw_j, const int* __restrict__ t_uw_w,
    const int* __restrict__ t_iw_j, const int* __restrict__ t_iw_w,
    unsigned* __restrict__ aoB)
{
    const int g = blockIdx.y;
    const int p = blockIdx.x & 1;
    const int tile = blockIdx.x >> 1;
    int y; const int* Vj; const int* Vw;
    switch (g * 2 + p) {
        case 0:  y = 2; Vj = i_uw_j; Vw = i_uw_w; break;   // g=0 (user table)
        case 1:  y = 4; Vj = t_uw_j; Vw = t_uw_w; break;
        case 2:  y = 0; Vj = u_iw_j; Vw = u_iw_w; break;   // g=1 (item table)
        case 3:  y = 5; Vj = t_iw_j; Vw = t_iw_w; break;
        case 4:  y = 1; Vj = u_tw_j; Vw = u_tw_w; break;   // g=2 (tag table)
        default: y = 3; Vj = i_tw_j; Vw = i_tw_w; break;
    }
    const float* v = (g == 0) ? vu : (g == 1) ? vi : vt;
    const unsigned* pre = preB + (size_t)y * NN * 32;
    const unsigned char* gw = gw8 + (size_t)g * (EE + 1) * 64;
    const unsigned char* jg = JG + (size_t)g * (NN + 1) * 192;
    unsigned*            out = aoB + (size_t)y * NN * 32;

    const int lane = threadIdx.x & 63;
    const int n = tile * 4 + (threadIdx.x >> 6);
    const int q = lane >> 4, r = lane & 15;

    // per-lane node-static data: features 4r..4r+3 (packed f16)
    const uint2 prep = *(const uint2*)(pre + (size_t)n * 32 + 2 * r);
    const h2 pre01 = __builtin_bit_cast(h2, prep.x);
    const h2 pre23 = __builtin_bit_cast(h2, prep.y);
    const float4 v4 = *(const float4*)(v + r * 4);
    const h2 v01h = __builtin_amdgcn_cvt_pkrtz(v4.x, v4.y);
    const h2 v23h = __builtin_amdgcn_cvt_pkrtz(v4.z, v4.w);

    // this lane's 4 neighbor slots: k = 4q..4q+3
    const int4 wi = *(const int4*)(Vw + n * 16 + q * 4);
    const int4 ji = *(const int4*)(Vj + n * 16 + q * 4);
    const int wid[4] = { wi.x, wi.y, wi.z, wi.w };
    const int jid[4] = { ji.x, ji.y, ji.z, ji.w };

    // issue ALL gathers first (12 independent loads in flight)
    unsigned gwv[4], gjv[4]; uint2 ejv[4];
    #pragma unroll
    for (int i = 0; i < 4; ++i)
        gwv[i] = *(const unsigned*)(gw + (size_t)wid[i] * 64 + r * 4);
    #pragma unroll
    for (int i = 0; i < 4; ++i) {
        const unsigned char* row = jg + (size_t)jid[i] * 192;
        gjv[i] = *(const unsigned*)(row + r * 4);
        ejv[i] = *(const uint2*)(row + 64 + r * 8);
    }

    // logits: x[k=4q+i] = sum_f relu(pre+gw+gj)*v, reduced over 16 r-lanes
    float xk[4];
    #pragma unroll
    for (int i = 0; i < 4; ++i) {
        h2 g01 = fp8toh<false>(gwv[i]);
        h2 g23 = fp8toh<true>(gwv[i]);
        h2 j01 = fp8toh<false>(gjv[i]);
        h2 j23 = fp8toh<true>(gjv[i]);
        h2 z01 = hmax0(pre01 + g01 + j01);
        h2 z23 = hmax0(pre23 + g23 + j23);
        float x = hdot(z01, v01h, 0.f);
        x = hdot(z23, v23h, x);
        x += __shfl_xor(x, 1, 64);
        x += __shfl_xor(x, 2, 64);
        x += __shfl_xor(x, 4, 64);
        x += __shfl_xor(x, 8, 64);
        xk[i] = x;
    }
    // softmax over 16 k (4 local regs x 4 q-groups)
    float m = fmaxf(fmaxf(xk[0], xk[1]), fmaxf(xk[2], xk[3]));
    m = fmaxf(m, __shfl_xor(m, 16, 64));
    m = fmaxf(m, __shfl_xor(m, 32, 64));
    float e0 = __expf(xk[0] - m), e1 = __expf(xk[1] - m);
    float e2 = __expf(xk[2] - m), e3 = __expf(xk[3] - m);
    float s = (e0 + e1) + (e2 + e3);
    s += __shfl_xor(s, 16, 64);
    s += __shfl_xor(s, 32, 64);
    const float inv = 1.f / s;

    // weighted ej sum (f32x2 -> v_pk_fma_f32; same per-component order)
    const float wgt[4] = { e0 * inv, e1 * inv, e2 * inv, e3 * inv };
    f32x2 A01; A01.x = 0.f; A01.y = 0.f;
    f32x2 A23; A23.x = 0.f; A23.y = 0.f;
    #pragma unroll
    for (int i = 0; i < 4; ++i) {
        f32x2 w2; w2.x = wgt[i]; w2.y = wgt[i];
        f32x2 e01; e01.x = bflo(ejv[i].x); e01.y = bfhi(ejv[i].x);
        f32x2 e23; e23.x = bflo(ejv[i].y); e23.y = bfhi(ejv[i].y);
        A01 = e01 * w2 + A01;
        A23 = e23 * w2 + A23;
    }
    float a0 = A01.x, a1 = A01.y, a2 = A23.x, a3 = A23.y;
    a0 += __shfl_xor(a0, 16, 64); a0 += __shfl_xor(a0, 32, 64);
    a1 += __shfl_xor(a1, 16, 64); a1 += __shfl_xor(a1, 32, 64);
    a2 += __shfl_xor(a2, 16, 64); a2 += __shfl_xor(a2, 32, 64);
    a3 += __shfl_xor(a3, 16, 64); a3 += __shfl_xor(a3, 32, 64);
    if (q == 0) {
        uint2 pk = { pack2(a0, a1), pack2(a2, a3) };
        *(uint2*)(out + (size_t)n * 32 + 2 * r) = pk;
    }
}

// ---------------------------------------------------------------------------
// tail: atten2 + convs + final linear, all MFMA (16x16x32 bf16). (unchanged)
// ---------------------------------------------------------------------------
__global__ __launch_bounds__(256, 3) void tail_kernel(
    const float* __restrict__ eu, const float* __restrict__ ei, const float* __restrict__ et,
    const unsigned* __restrict__ aoB,
    const float* __restrict__ U, const float* __restrict__ q, const float* __restrict__ p,
    const float* __restrict__ Wbit, const float* __restrict__ Wv1,
    const float* __restrict__ Wv2, const float* __restrict__ Wv3,
    const float* __restrict__ Wf, const float* __restrict__ bfv,
    float* __restrict__ out)
{
    __shared__ __align__(16) unsigned short uitA[48 * 72];
    __shared__ __align__(16) unsigned short eNA[48 * 72];
    __shared__ __align__(16) unsigned short wcf[6 * 64 * 8];
    __shared__ __align__(16) unsigned short c_sh[16 * 584];
    __shared__ float G_sh[48 * 52];
    __shared__ float xpart[4 * 48];
    __shared__ float bcoef[16 * 4];

    const int t = threadIdx.x;
    const int lane = t & 63;
    const int wv = t >> 6;
    const int l15 = lane & 15;
    const int quad = lane >> 4;
    const int type = blockIdx.y;
    const float* xf = (type == 0) ? eu : (type == 1) ? ei : et;
    const int cw = wv * 16 + l15;
    const float qv = q[cw], pv = p[cw], bfb = bfv[cw];

    float wb[8][3];
    #pragma unroll
    for (int c = 0; c < 8; ++c)
        #pragma unroll
        for (int s = 0; s < 3; ++s) wb[c][s] = Wbit[c * 3 + s];

    bf16x8 ufrag[2];
    #pragma unroll
    for (int ks = 0; ks < 2; ++ks)
        #pragma unroll
        for (int j = 0; j < 8; ++j) {
            int f = ks * 32 + quad * 8 + j;
            ufrag[ks][j] = (short)f2bf(U[f * 64 + cw]);
        }
    bf16x8 wff[18];
    #pragma unroll
    for (int ks = 0; ks < 18; ++ks)
        #pragma unroll
        for (int j = 0; j < 8; ++j) {
            int k = ks * 32 + quad * 8 + j;
            float w = (k < 560) ? Wf[(size_t)k * 64 + cw] : 0.f;
            wff[ks][j] = (short)f2bf(w);
        }
    for (int slot = t; slot < 384; slot += 256) {
        int fi = slot >> 6, l = slot & 63;
        int nt_ = fi >> 1, ks = fi & 1;
        int r = nt_ * 16 + (l & 15);
        unsigned short vals[8];
        #pragma unroll
        for (int j = 0; j < 8; ++j) {
            int f = ks * 32 + (l >> 4) * 8 + j;
            float wv_;
            if (r < 8)       wv_ = Wv1[r * 64 + f];
            else if (r < 24) { int u = r - 8;  wv_ = Wv2[(u >> 1) * 128 + (u & 1) * 64 + f]; }
            else             { int u = r - 24; wv_ = Wv3[(u / 3) * 192 + (u % 3) * 64 + f]; }
            vals[j] = f2bf(wv_);
        }
        uint4 pk = { (unsigned)vals[0] | ((unsigned)vals[1] << 16),
                     (unsigned)vals[2] | ((unsigned)vals[3] << 16),
                     (unsigned)vals[4] | ((unsigned)vals[5] << 16),
                     (unsigned)vals[6] | ((unsigned)vals[7] << 16) };
        *(uint4*)&wcf[slot * 8] = pk;
    }

    for (int tile = blockIdx.x; tile < NT; tile += gridDim.x) {
        const int nodeBase = tile * 16;
        __syncthreads();
        #pragma unroll
        for (int i = 0; i < 3; ++i) {
            int idx = t + i * 256;
            int row = idx >> 4, cg = idx & 15;
            int nl = row / 3, s = row - nl * 3;
            int n = nodeBase + nl;
            uint2 pk;
            if (s == type) {
                float4 v4 = (n < NN) ? *(const float4*)(xf + (size_t)n * 64 + cg * 4)
                                     : make_float4(0.f, 0.f, 0.f, 0.f);
                pk.x = pack2(v4.x, v4.y); pk.y = pack2(v4.z, v4.w);
            } else {
                int aoidx = (type == 0) ? (s - 1)
                          : (type == 1) ? ((s == 0) ? 2 : 3)
                                        : ((s == 0) ? 4 : 5);
                pk = (n < NN) ? *(const uint2*)(aoB + ((size_t)aoidx * NN + n) * 32 + cg * 2)
                              : make_uint2(0u, 0u);
            }
            *(uint2*)&uitA[row * 72 + cg * 4] = pk;
        }
        __syncthreads();
        {
            f32x4 av[3];
            #pragma unroll
            for (int mt = 0; mt < 3; ++mt) { av[mt].x = 0; av[mt].y = 0; av[mt].z = 0; av[mt].w = 0; }
            #pragma unroll
            for (int mt = 0; mt < 3; ++mt)
                #pragma unroll
                for (int ks = 0; ks < 2; ++ks) {
                    bf16x8 a = *(const bf16x8*)&uitA[(mt * 16 + l15) * 72 + ks * 32 + quad * 8];
                    av[mt] = __builtin_amdgcn_mfma_f32_16x16x32_bf16(a, ufrag[ks], av[mt], 0, 0, 0);
                }
            #pragma unroll
            for (int mt = 0; mt < 3; ++mt)
                #pragma unroll
                for (int r = 0; r < 4; ++r) {
                    float val = fmaxf(av[mt][r] + qv, 0.f) * pv;
                    val += __shfl_xor(val, 1, 64); val += __shfl_xor(val, 2, 64);
                    val += __shfl_xor(val, 4, 64); val += __shfl_xor(val, 8, 64);
                    if (l15 == 0) xpart[wv * 48 + mt * 16 + quad * 4 + r] = val;
                }
        }
        __syncthreads();
        if (t < 16) {
            float xv[3];
            #pragma unroll
            for (int s = 0; s < 3; ++s)
                xv[s] = xpart[t * 3 + s] + xpart[48 + t * 3 + s]
                      + xpart[96 + t * 3 + s] + xpart[144 + t * 3 + s];
            float mm = fmaxf(xv[0], fmaxf(xv[1], xv[2]));
            float e0 = __expf(xv[0] - mm), e1 = __expf(xv[1] - mm), e2 = __expf(xv[2] - mm);
            float inv = 1.f / (e0 + e1 + e2);
            bcoef[t * 4 + 0] = e0 * inv; bcoef[t * 4 + 1] = e1 * inv; bcoef[t * 4 + 2] = e2 * inv;
        }
        __syncthreads();
        #pragma unroll
        for (int i = 0; i < 2; ++i) {
            int task = t + i * 256;
            int nl = task >> 5, fp = task & 31;
            float b0 = bcoef[nl * 4], b1 = bcoef[nl * 4 + 1], b2 = bcoef[nl * 4 + 2];
            unsigned u0 = *(const unsigned*)&uitA[(nl * 3 + 0) * 72 + fp * 2];
            unsigned u1 = *(const unsigned*)&uitA[(nl * 3 + 1) * 72 + fp * 2];
            unsigned u2 = *(const unsigned*)&uitA[(nl * 3 + 2) * 72 + fp * 2];
            float e0l = b0 * bflo(u0), e0h = b0 * bfhi(u0);
            float e1l = b1 * bflo(u1), e1h = b1 * bfhi(u1);
            float e2l = b2 * bflo(u2), e2h = b2 * bfhi(u2);
            *(unsigned*)&eNA[(nl * 3 + 0) * 72 + fp * 2] = pack2(e0l, e0h);
            *(unsigned*)&eNA[(nl * 3 + 1) * 72 + fp * 2] = pack2(e1l, e1h);
            *(unsigned*)&eNA[(nl * 3 + 2) * 72 + fp * 2] = pack2(e2l, e2h);
            #pragma unroll
            for (int c = 0; c < 8; ++c) {
                float lo = fmaxf(wb[c][0] * e0l + wb[c][1] * e1l + wb[c][2] * e2l, 0.f);
                float hi = fmaxf(wb[c][0] * e0h + wb[c][1] * e1h + wb[c][2] * e2h, 0.f);
                *(unsigned*)&c_sh[nl * 584 + c * 64 + fp * 2] = pack2(lo, hi);
            }
        }
        __syncthreads();
        #pragma unroll
        for (int pi = 0; pi < 3; ++pi) {
            int pr = wv + pi * 4;
            if (pr < 9) {
                int mm = pr / 3, nn_ = pr - mm * 3;
                f32x4 g; g.x = 0; g.y = 0; g.z = 0; g.w = 0;
                #pragma unroll
                for (int ks = 0; ks < 2; ++ks) {
                    bf16x8 a = *(const bf16x8*)&eNA[(mm * 16 + l15) * 72 + ks * 32 + quad * 8];
                    bf16x8 b = *(const bf16x8*)&wcf[((nn_ * 2 + ks) * 64 + lane) * 8];
                    g = __builtin_amdgcn_mfma_f32_16x16x32_bf16(a, b, g, 0, 0, 0);
                }
                #pragma unroll
                for (int r = 0; r < 4; ++r)
                    G_sh[(mm * 16 + quad * 4 + r) * 52 + nn_ * 16 + l15] = g[r];
            }
        }
        __syncthreads();
        #pragma unroll
        for (int i = 0; i < 4; ++i) {
            int task = t + i * 256;
            int vvv = task >> 4, nl = task & 15;
            unsigned short res = 0;
            if (vvv < 24) {
                int c = vvv / 3, s = vvv - c * 3;
                res = f2bf(fmaxf(G_sh[(nl * 3 + s) * 52 + c], 0.f));
            } else if (vvv < 40) {
                int u = vvv - 24, c = u >> 1, s = u & 1;
                float val = G_sh[(nl * 3 + s) * 52 + 8 + 2 * c]
                          + G_sh[(nl * 3 + s + 1) * 52 + 8 + 2 * c + 1];
                res = f2bf(fmaxf(val, 0.f));
            } else if (vvv < 48) {
                int c = vvv - 40;
                float val = G_sh[(nl * 3 + 0) * 52 + 24 + 3 * c]
                          + G_sh[(nl * 3 + 1) * 52 + 24 + 3 * c + 1]
                          + G_sh[(nl * 3 + 2) * 52 + 24 + 3 * c + 2];
                res = f2bf(fmaxf(val, 0.f));
            }
            c_sh[nl * 584 + 512 + vvv] = res;
        }
        __syncthreads();
        {
            f32x4 acc; acc.x = 0; acc.y = 0; acc.z = 0; acc.w = 0;
            const unsigned short* ap = &c_sh[l15 * 584 + quad * 8];
            #pragma unroll
            for (int ks = 0; ks < 18; ++ks) {
                bf16x8 a = *(const bf16x8*)(ap + ks * 32);
                acc = __builtin_amdgcn_mfma_f32_16x16x32_bf16(a, wff[ks], acc, 0, 0, 0);
            }
            float* outT = out + (size_t)type * NN * 64;
            #pragma unroll
            for (int r = 0; r < 4; ++r) {
                int node = nodeBase + quad * 4 + r;
                if (node < NN) outT[(size_t)node * 64 + cw] = fmaxf(acc[r] + bfb, 0.f);
            }
        }
    }
}

// ---------------------------------------------------------------------------
extern "C" void kernel_launch(void* const* d_in, const int* in_sizes, int n_in,
                              void* d_out, int out_size, void* d_ws, size_t ws_size,
                              hipStream_t stream)
{
    const float* eu = (const float*)d_in[0];
    const float* ei = (const float*)d_in[1];
    const float* et = (const float*)d_in[2];
    const float* ew = (const float*)d_in[3];
    const int* u_iw_j = (const int*)d_in[4];
    const int* u_iw_w = (const int*)d_in[5];
    const int* u_tw_j = (const int*)d_in[6];
    const int* u_tw_w = (const int*)d_in[7];
    const int* i_uw_j = (const int*)d_in[8];
    const int* i_uw_w = (const int*)d_in[9];
    const int* i_tw_j = (const int*)d_in[10];
    const int* i_tw_w = (const int*)d_in[11];
    const int* t_uw_j = (const int*)d_in[12];
    const int* t_uw_w = (const int*)d_in[13];
    const int* t_iw_j = (const int*)d_in[14];
    const int* t_iw_w = (const int*)d_in[15];
    const float* W1_user = (const float*)d_in[16];
    const float* W2_user = (const float*)d_in[17];
    const float* b_user  = (const float*)d_in[18];
    const float* v_user  = (const float*)d_in[19];
    const float* W1_item = (const float*)d_in[20];
    const float* W2_item = (const float*)d_in[21];
    const float* b_item  = (const float*)d_in[22];
    const float* v_item  = (const float*)d_in[23];
    const float* W1_tag  = (const float*)d_in[24];
    const float* W2_tag  = (const float*)d_in[25];
    const float* b_tag   = (const float*)d_in[26];
    const float* v_tag   = (const float*)d_in[27];
    const float* U    = (const float*)d_in[28];
    const float* q    = (const float*)d_in[29];
    const float* p    = (const float*)d_in[30];
    const float* Wbit = (const float*)d_in[31];
    const float* Wv1  = (const float*)d_in[32];
    const float* Wv2  = (const float*)d_in[33];
    const float* Wv3  = (const float*)d_in[34];
    const float* Wf   = (const float*)d_in[35];
    const float* bfv  = (const float*)d_in[36];
    float* out = (float*)d_out;

    // ---- workspace (~110 MB):
    // gw8: 3*(E+1)*64 B | preB: 6*N*128 B | JG: 3*(N+1)*192 B | aoB: 6*N*128 B
    unsigned char* gw8 = (unsigned char*)d_ws;
    unsigned* preB = (unsigned*)(gw8 + (size_t)3 * (EE + 1) * 64);
    unsigned char* JG = (unsigned char*)(preB + (size_t)6 * NN * 32);
    unsigned* aoB = (unsigned*)(JG + (size_t)3 * (NN + 1) * 192);

    const dim3 blk(256);

    head_kernel<<<ET128 + 3 * NT128, blk, 0, stream>>>(
        ew, eu, ei, et,
        W1_user, W1_item, W1_tag, W2_user, W2_item, W2_tag,
        b_user, b_item, b_tag, gw8, preB, JG);

    atten1_kernel<<<dim3(2 * (NN / 4), 3), blk, 0, stream>>>(
        preB, gw8, JG, v_user, v_item, v_tag,
        u_iw_j, u_iw_w, u_tw_j, u_tw_w, i_uw_j, i_uw_w,
        i_tw_j, i_tw_w, t_uw_j, t_uw_w, t_iw_j, t_iw_w, aoB);

    tail_kernel<<<dim3(256, 3), blk, 0, stream>>>(
        eu, ei, et, aoB,
        U, q, p, Wbit, Wv1, Wv2, Wv3, Wf, bfv, out);
}